// Round 7
// baseline (129.243 us; speedup 1.0000x reference)
//
#include <hip/hip_runtime.h>
#include <hip/hip_bf16.h>

// Shapes: B=2, C=256, H=W=24 (HW=576), G=16, Cg=16, GRID=25, AC=6400, Mg=400
// Inputs fp32, output fp32.
// ws layout (fp32): h1f[16*2*256*576] | pooled[16*2*6400] | aff[16*2*16]
// dur_us floor: harness d_ws poison fill = 43.2 us (256 MiB @ ~6.2 TB/s), unavoidable.

typedef __attribute__((ext_vector_type(8))) short short8;
typedef __attribute__((ext_vector_type(4))) short short4v;
typedef __attribute__((ext_vector_type(4))) float f32x4;

static __device__ __forceinline__ short f2bf(float x) {
    unsigned u = __float_as_uint(x);
    unsigned r = (u + 0x7fffu + ((u >> 16) & 1u)) >> 16;   // RNE
    return (short)r;
}

// Fused: [3x3 grouped conv + BN + ReLU] -> LDS -> [1x1 conv(pad=1) + BN + ReLU
// + 26x26 avg-pool]. One block per (i,b,g); g doubles as k2's group index k.
// Phase 1 (conv): D(16co x 576px) = W1'(16x144) * im2col(144x576) + bias1, K
// padded 144->160 (5 K-steps, 2 taps each). Phase 2 (pool): per-m-tile
// D2 = W2'(16x16) * h(16x576-tile) + bias2, relu, column-reduce, pool.
__global__ __launch_bounds__(256) void k12_fused(
    const float* __restrict__ xin,
    const float* __restrict__ W1,
    const float* __restrict__ g1, const float* __restrict__ b1,
    const float* __restrict__ m1, const float* __restrict__ v1,
    const float* __restrict__ W2,
    const float* __restrict__ g2, const float* __restrict__ b2,
    const float* __restrict__ m2, const float* __restrict__ v2,
    float* __restrict__ h1f,
    float* __restrict__ pooled)
{
    // LDS union: phase1 {xs 33696 B, wA 6400 B} / phase2 {hsb 23040, wlb 12800,
    // psum 6400, bias2 1600} = 43840 B total.
    __shared__ __align__(16) char smem[43840];
    short* xs    = (short*)smem;               // [row27][col26][ci pitch24]
    short* wA    = (short*)(smem + 33696);     // [kk5][co16][k pitch40]
    short* hsb   = (short*)smem;               // [s576][j pitch20]
    short* wlb   = (short*)(smem + 23040);     // [m400][j16]
    float* psum  = (float*)(smem + 35840);     // [wave4][m400]
    float* bias2 = (float*)(smem + 42240);     // [m400]
    __shared__ float scale1[16], bias1[16];

    int bid = blockIdx.x;                      // i*32 + b*16 + g
    int i = bid >> 5, b = (bid >> 4) & 1, g = bid & 15;
    int t = threadIdx.x;

    // ---- phase 1 staging: zero-pad image, fold BN1, scale W1 ----
    int* xz = (int*)xs;
    for (int idx = t; idx < 27*26*12; idx += 256) xz[idx] = 0;
    if (t < 16) {
        int c = i*256 + g*16 + t;
        float sc = g1[c] * rsqrtf(v1[c] + 1e-5f);
        scale1[t] = sc;
        bias1[t]  = b1[c] - m1[c] * sc;
    }
    __syncthreads();

    const float* xb = &xin[(b*256 + g*16)*576];
    for (int idx = t; idx < 9216; idx += 256) {
        int ci = idx / 576; int s = idx - ci*576;
        int y = s / 24; int x = s - y*24;
        xs[((y+1)*26 + (x+1))*24 + ci] = f2bf(xb[idx]);
    }
    const float* wb = &W1[(i*256 + g*16)*144];    // [co][ci][9]
    for (int idx = t; idx < 2560; idx += 256) {
        int kk = idx >> 9, rem = idx & 511, co = rem >> 5, k = rem & 31;
        int tap = 2*kk + (k >> 4), ci = k & 15;
        float val = (tap < 9) ? wb[co*144 + ci*9 + tap] * scale1[co] : 0.f;
        wA[(kk*16 + co)*40 + k] = f2bf(val);
    }
    __syncthreads();

    // ---- phase 1 compute: 9 pixel-tiles per wave, 5 MFMA each ----
    int l = t & 63, w = t >> 6;
    int quad = l >> 4, col = l & 15;
    {
        int ci0 = (quad & 1) * 8;
        short8 afr[5];
#pragma unroll
        for (int kk = 0; kk < 5; kk++)
            afr[kk] = *(const short8*)&wA[(kk*16 + col)*40 + quad*8];
        f32x4 cb1 = *(const f32x4*)&bias1[quad*4];

        const int offE[5] = {0, 48, 648, 1248, 1296};     // taps 0,2,4,6,8
        const int offO[5] = {24, 624, 672, 1272, 1872};   // taps 1,3,5,7,9
        int off[5];
#pragma unroll
        for (int kk = 0; kk < 5; kk++) off[kk] = (quad >= 2) ? offO[kk] : offE[kk];

        f32x4 dreg[9];
#pragma unroll 3
        for (int tt = 0; tt < 9; tt++) {
            int s = (w*9 + tt)*16 + col;
            int y = s / 24; int x = s - y*24;
            int base = (y*26 + x)*24 + ci0;
            f32x4 acc = cb1;
#pragma unroll
            for (int kk = 0; kk < 5; kk++) {
                short8 bf = *(const short8*)&xs[base + off[kk]];
                acc = __builtin_amdgcn_mfma_f32_16x16x32_bf16(afr[kk], bf, acc, 0, 0, 0);
            }
#pragma unroll
            for (int r = 0; r < 4; r++) acc[r] = fmaxf(acc[r], 0.f);
            dreg[tt] = acc;
        }
        __syncthreads();   // all xs/wA reads done; safe to overlay hsb

        // write h to LDS (bf16, [s][j] pitch 20) and to global fp32 for k4
        float* hout = &h1f[((i*2 + b)*256 + g*16)*576];
#pragma unroll
        for (int tt = 0; tt < 9; tt++) {
            int s = (w*9 + tt)*16 + col;
            f32x4 acc = dreg[tt];
            unsigned p0 = (unsigned)(unsigned short)f2bf(acc[0]) |
                          ((unsigned)(unsigned short)f2bf(acc[1]) << 16);
            unsigned p1 = (unsigned)(unsigned short)f2bf(acc[2]) |
                          ((unsigned)(unsigned short)f2bf(acc[3]) << 16);
            uint2 pk = {p0, p1};
            *(uint2*)&hsb[s*20 + quad*4] = pk;
#pragma unroll
            for (int r = 0; r < 4; r++)
                hout[(quad*4 + r)*576 + s] = acc[r];
        }
    }

    // ---- phase 2 staging: W2*s2 -> wlb, bias2 ----
    for (int m = t; m < 400; m += 256) {
        int o = i*6400 + g*400 + m;
        float s2 = g2[o] * rsqrtf(v2[o] + 1e-5f);
        bias2[m] = b2[o] - m2[o] * s2;
        const float4* wr = (const float4*)&W2[o*16];
#pragma unroll
        for (int q = 0; q < 4; q++) {
            float4 wv = wr[q];
            wlb[m*16 + q*4 + 0] = f2bf(wv.x * s2);
            wlb[m*16 + q*4 + 1] = f2bf(wv.y * s2);
            wlb[m*16 + q*4 + 2] = f2bf(wv.z * s2);
            wlb[m*16 + q*4 + 3] = f2bf(wv.w * s2);
        }
    }
    __syncthreads();

    // ---- phase 2 compute: D2 = W2'(400x16) * h(16x576) + bias2; pool relu ----
    int half = l >> 4;          // quads 2,3 are K-padding (zero)
    {
        short8 bfr[9];
#pragma unroll
        for (int u = 0; u < 9; u++) {
            if (l < 32) {
                const short* p = &hsb[((w*9 + u)*16 + col)*20 + half*8];
                short4v lo = *(const short4v*)p;
                short4v hi = *(const short4v*)(p + 4);
                short8 f; f[0]=lo.x; f[1]=lo.y; f[2]=lo.z; f[3]=lo.w;
                          f[4]=hi.x; f[5]=hi.y; f[6]=hi.z; f[7]=hi.w;
                bfr[u] = f;
            } else {
                bfr[u] = (short8)0;
            }
        }

        for (int mt = 0; mt < 25; mt++) {
            short8 af = (short8)0;
            if (l < 32)
                af = *(const short8*)&wlb[(mt*16 + col)*16 + half*8];

            f32x4 cb = *(const f32x4*)&bias2[mt*16 + half*4];

            f32x4 d[9];
#pragma unroll
            for (int u = 0; u < 9; u++)
                d[u] = __builtin_amdgcn_mfma_f32_16x16x32_bf16(af, bfr[u], cb, 0, 0, 0);

            float p0=0.f, p1=0.f, p2=0.f, p3=0.f;
#pragma unroll
            for (int u = 0; u < 9; u++) {
                p0 += fmaxf(d[u][0], 0.f);
                p1 += fmaxf(d[u][1], 0.f);
                p2 += fmaxf(d[u][2], 0.f);
                p3 += fmaxf(d[u][3], 0.f);
            }
#pragma unroll
            for (int msk = 1; msk < 16; msk <<= 1) {
                p0 += __shfl_xor(p0, msk);
                p1 += __shfl_xor(p1, msk);
                p2 += __shfl_xor(p2, msk);
                p3 += __shfl_xor(p3, msk);
            }
            if (col == 0) {
                f32x4 pv = {p0, p1, p2, p3};     // rows m = mt*16 + half*4 + r
                *(f32x4*)&psum[w*400 + mt*16 + half*4] = pv;
            }
        }
    }
    __syncthreads();

    const float inv = 1.f / 676.f;   // 26x26 pool incl. 100 border px
    for (int m = t; m < 400; m += 256) {
        float s = psum[0*400+m] + psum[1*400+m] + psum[2*400+m] + psum[3*400+m];
        float be = bias2[m];
        pooled[(i*2+b)*6400 + g*400 + m] = (s + 100.f * fmaxf(be, 0.f)) * inv;
    }
}

__global__ __launch_bounds__(256) void k3_aff(const float* __restrict__ pooled,
                                              float* __restrict__ aff)
{
    __shared__ float th[400];
    __shared__ float parts[256];
    int bid = blockIdx.x;           // i*2 + b
    int i = bid >> 1;
    int t = threadIdx.x;
    const float* pb = &pooled[bid*6400];
    for (int idx = t; idx < 400; idx += 256) th[idx] = pb[i*400 + idx];
    __syncthreads();
    int l = t >> 4, p = t & 15;
    float sum = 0.f;
    const float* pl = &pb[l*400];
    for (int m = p*25; m < p*25 + 25; m++) sum = fmaf(th[m], pl[m], sum);
    parts[t] = sum;
    __syncthreads();
    if (t < 16) {
        float s = 0.f;
        for (int pp = 0; pp < 16; pp++) s += parts[t*16 + pp];
        aff[bid*16 + t] = s * (1.f/16.f);
    }
}

__global__ __launch_bounds__(256) void k4_out(const float* __restrict__ h1f,
                                              const float* __restrict__ aff,
                                              float* __restrict__ out)
{
    __shared__ float a0[16], a1[16];
    int bid = blockIdx.x;           // i*32 + q*16 + cg
    int i = bid >> 5, q = (bid >> 4) & 1, cg = bid & 15;
    int t = threadIdx.x;
    if (t < 16) a0[t] = aff[(i*2+0)*16 + t];
    else if (t < 32) a1[t-16] = aff[(i*2+1)*16 + (t-16)];
    __syncthreads();
    const float* hb = &h1f[((i*2+q)*256 + cg)*576];
    int ch = i*32 + q*16 + cg;
    for (int s = t; s < 576; s += 256) {
        float acc0 = 0.f, acc1 = 0.f;
#pragma unroll
        for (int k = 0; k < 16; k++) {
            float v = hb[k*9216 + s];
            acc0 = fmaf(a0[k], v, acc0);
            acc1 = fmaf(a1[k], v, acc1);
        }
        out[ch*576 + s]         = acc0;
        out[(512 + ch)*576 + s] = acc1;
    }
}

extern "C" void kernel_launch(void* const* d_in, const int* in_sizes, int n_in,
                              void* d_out, int out_size, void* d_ws, size_t ws_size,
                              hipStream_t stream)
{
    const float* x  = (const float*)d_in[0];
    const float* W1 = (const float*)d_in[1];
    const float* g1 = (const float*)d_in[2];
    const float* b1 = (const float*)d_in[3];
    const float* m1 = (const float*)d_in[4];
    const float* v1 = (const float*)d_in[5];
    const float* W2 = (const float*)d_in[6];
    const float* g2 = (const float*)d_in[7];
    const float* b2 = (const float*)d_in[8];
    const float* m2 = (const float*)d_in[9];
    const float* v2 = (const float*)d_in[10];

    float* h1f    = (float*)d_ws;
    float* pooled = h1f + 16*2*256*576;     // +4,718,592 floats
    float* aff    = pooled + 16*2*6400;     // +204,800 floats

    float* out = (float*)d_out;

    hipLaunchKernelGGL(k12_fused, dim3(512), dim3(256), 0, stream,
                       x, W1, g1, b1, m1, v1, W2, g2, b2, m2, v2, h1f, pooled);
    hipLaunchKernelGGL(k3_aff,    dim3(32),  dim3(256), 0, stream,
                       pooled, aff);
    hipLaunchKernelGGL(k4_out,    dim3(512), dim3(256), 0, stream,
                       h1f, aff, out);
}